// Round 8
// baseline (36.473 us; speedup 1.0000x reference)
//
#include <hip/hip_runtime.h>

// ---------------- problem constants ----------------
#define B_    8192
#define K_    784      // IN_DIM
#define KP    832      // K padded to 13*64
#define NKB   13       // K blocks of 64
#define RP    1024     // unique w1 rows = HIDDEN/CF
#define HID   4096
#define OD    10
#define TS2   10240    // OUT_DIM*HIDDEN/CF

#define NB_X  3328     // 8192*104/256
#define NB_S  416      // 1024*832/8/256  (Sfrag, fragment-ordered)
#define NB_F  64       // 16*1024/256     (Vfrag)
#define NB_Z  80       // 80*256*4 = 81920 floats of out zeroing

typedef __attribute__((ext_vector_type(8))) short  bf16x8;
typedef __attribute__((ext_vector_type(4))) float  f32x4;

__device__ __forceinline__ unsigned short f2bf(float f) {
    unsigned u = __builtin_bit_cast(unsigned, f);
    u += 0x7fffu + ((u >> 16) & 1u);          // RNE
    return (unsigned short)(u >> 16);
}

// ================= merged prep kernel =====================================
// blocks [0, NB_X)     : x -> bf16, padded + per-row 8-slot swizzle (round-6)
// blocks [NB_X, +NB_S) : tile1 -> +/-1 bf16 in MFMA B-FRAGMENT order:
//     Sfrag[(((rb*13 + kb)*2 + ks)*64 + l)*8 + e] =
//         sgn(t1[(rb*16 + (l&15))*784 + kb*64 + ks*32 + (l>>4)*8 + e])
//     (0 beyond col 784). rb = B-row/16.
// blocks [.., +NB_F)   : Vfrag (bf16, MFMA B-fragment order, o pad to 16)
// blocks [.., +NB_Z)   : zero out[]
__global__ __launch_bounds__(256) void prep(
    const float* __restrict__ x, const int* __restrict__ t1,
    const int* __restrict__ t2, const float* __restrict__ a1,
    const float* __restrict__ a2,
    unsigned short* __restrict__ Xsw, unsigned short* __restrict__ Sfrag,
    unsigned short* __restrict__ Vfrag, float* __restrict__ out)
{
    const int b = blockIdx.x;
    if (b < NB_X) {
        const int id = b * 256 + threadIdx.x;
        const int row = id / 104;
        const int rem = id - row * 104;
        const int kb = rem >> 3;
        const int s  = rem & 7;
        const int kk = kb * 64 + ((s ^ (row & 7)) << 3);
        bf16x8 v;
        if (kk < K_) {
            const float* xp = x + (size_t)row * K_ + kk;
            f32x4 a = *(const f32x4*)xp;
            f32x4 c = *(const f32x4*)(xp + 4);
            v[0] = (short)f2bf(a.x); v[1] = (short)f2bf(a.y);
            v[2] = (short)f2bf(a.z); v[3] = (short)f2bf(a.w);
            v[4] = (short)f2bf(c.x); v[5] = (short)f2bf(c.y);
            v[6] = (short)f2bf(c.z); v[7] = (short)f2bf(c.w);
        } else {
            v = (bf16x8)0;
        }
        *(bf16x8*)(Xsw + (size_t)row * KP + kb * 64 + s * 8) = v;
    } else if (b < NB_X + NB_S) {
        const int id  = (b - NB_X) * 256 + threadIdx.x;   // < 106,496
        const int l   = id & 63;
        const int fid = id >> 6;                          // (rb*13 + kb)*2 + ks
        const int ks  = fid & 1;
        const int kf  = fid >> 1;
        const int rb  = kf / 13;
        const int kb  = kf - rb * 13;
        const int row = rb * 16 + (l & 15);
        const int col0 = kb * 64 + ks * 32 + ((l >> 4) << 3);
        bf16x8 v;
        #pragma unroll
        for (int e = 0; e < 8; ++e) {
            const int col = col0 + e;
            v[e] = (col < K_)
                 ? (short)(t1[(size_t)row * K_ + col] ? 0x3F80 : 0xBF80)
                 : (short)0;
        }
        *(bf16x8*)(Sfrag + (size_t)id * 8) = v;
    } else if (b < NB_X + NB_S + NB_F) {
        const int id = (b - NB_X - NB_S) * 256 + threadIdx.x;   // < 16384
        const int o = id >> 10;           // 0..15 (10..15 are zero pad)
        const int r = id & 1023;
        float v = 0.f;
        if (o < OD) {
            #pragma unroll
            for (int c = 0; c < 4; ++c) {
                const int idx = o * HID + c * RP + r;
                const int ch  = idx / TS2;
                const float w2v = a2[ch] * (float)(2 * t2[idx - ch * TS2] - 1);
                v = fmaf(a1[c], w2v, v);
            }
        }
        Vfrag[(r >> 5) * 512 + (o + 16 * ((r >> 3) & 3)) * 8 + (r & 7)] = f2bf(v);
    } else {
        const int id = (b - NB_X - NB_S - NB_F) * 256 + threadIdx.x;
        ((f32x4*)out)[id] = (f32x4){0.f, 0.f, 0.f, 0.f};
    }
}

// ================= GEMM1 + fused layer 2 ==================================
// Round-6 structure (128x128 tile, BK=64 single-buffered A, 2 syncthreads/
// step, 4 waves 2x2, 512 blocks XCD-chunked = 2/CU) EXCEPT: B operand comes
// straight from L2 via coalesced register loads of the fragment-ordered
// Sfrag (whole S = 1.7 MB, L2-resident per XCD). Halves LDS reads + staging.
// Epilogue: relu->bf16->LDS overlay, mini-GEMM vs Vfrag, atomicAdd.
__global__ __launch_bounds__(256, 2) void gemm1(const unsigned short* __restrict__ Xsw,
                                                const unsigned short* __restrict__ Sfrag,
                                                const unsigned short* __restrict__ Vfrag,
                                                float* __restrict__ out) {
    __shared__ unsigned short SH[16384];       // 32 KB: [0,8K)=A stage, all=Hlds

    const int tid  = threadIdx.x;
    const int lane = tid & 63;
    const int wid  = tid >> 6;

    // bijective XCD-chunked swizzle: XCD k owns bm-tiles [8k, 8k+8) x all bn
    const int swz = (blockIdx.x & 7) * 64 + (blockIdx.x >> 3);
    const int bm  = (swz >> 3) * 128;
    const int bn  = (swz & 7) * 128;

    const int wr = (wid >> 1) * 64;
    const int wc = (wid & 1) * 64;

    const int srow   = lane >> 3;              // 0..7 rows per 1KB chunk
    const int sinrow = (lane & 7) << 3;        // ushort offset within 128B row

    // B fragment base pointers: frag (rb0+ni, kb, ks) lives at
    //   Sfrag + ((rb0+ni)*26 + kb*2 + ks)*512 + lane*8     (ushort units)
    const int rb0 = (bn + wc) >> 4;
    const unsigned short* bp0 = Sfrag + (size_t)(rb0 + 0) * 13312 + lane * 8;
    const unsigned short* bp1 = Sfrag + (size_t)(rb0 + 1) * 13312 + lane * 8;
    const unsigned short* bp2 = Sfrag + (size_t)(rb0 + 2) * 13312 + lane * 8;
    const unsigned short* bp3 = Sfrag + (size_t)(rb0 + 3) * 13312 + lane * 8;

    f32x4 acc[4][4] = {};

    for (int kb = 0; kb < NKB; ++kb) {
        // ---- stage A K-block kb into LDS (4 x 1KB gload_lds per wave) ----
        #pragma unroll
        for (int i = 0; i < 4; ++i) {
            const int offB = wid * 4096 + i * 1024;   // bytes within 8KB tile
            const int row  = (offB >> 7) + srow;
            const unsigned short* ga = Xsw + (size_t)(bm + row) * KP + kb * 64 + sinrow;
            __builtin_amdgcn_global_load_lds(
                (const __attribute__((address_space(1))) void*)ga,
                (__attribute__((address_space(3))) void*)(&SH[offB >> 1]),
                16, 0, 0);
        }
        // ---- load this kb's 8 B fragments into registers (coalesced L2) ----
        const int ko = kb * 1024;                  // ushort offset per K-block
        bf16x8 bfr[2][4];
        bfr[0][0] = *(const bf16x8*)(bp0 + ko);
        bfr[0][1] = *(const bf16x8*)(bp1 + ko);
        bfr[0][2] = *(const bf16x8*)(bp2 + ko);
        bfr[0][3] = *(const bf16x8*)(bp3 + ko);
        bfr[1][0] = *(const bf16x8*)(bp0 + ko + 512);
        bfr[1][1] = *(const bf16x8*)(bp1 + ko + 512);
        bfr[1][2] = *(const bf16x8*)(bp2 + ko + 512);
        bfr[1][3] = *(const bf16x8*)(bp3 + ko + 512);

        __syncthreads();                       // A landed (vmcnt drain) + B ready

        #pragma unroll
        for (int ks = 0; ks < 2; ++ks) {
            bf16x8 af[4];
            const int t = ks * 4 + (lane >> 4);
            #pragma unroll
            for (int mi = 0; mi < 4; ++mi) {
                const int row = wr + mi * 16 + (lane & 15);
                af[mi] = *(const bf16x8*)&SH[row * 64 + ((t ^ (row & 7)) << 3)];
            }
            #pragma unroll
            for (int mi = 0; mi < 4; ++mi)
                #pragma unroll
                for (int ni = 0; ni < 4; ++ni)
                    acc[mi][ni] = __builtin_amdgcn_mfma_f32_16x16x32_bf16(
                        af[mi], bfr[ks][ni], acc[mi][ni], 0, 0, 0);
        }
        __syncthreads();                       // all reads done before restage
    }

    // ---- fused epilogue ----------------------------------------------------
    // 1) relu(acc) -> bf16 -> Hlds[128][128] (overlay SH; col-slot XOR swizzle)
    unsigned short* Hlds = &SH[0];             // 128*128 ushorts = 32 KB
    #pragma unroll
    for (int mi = 0; mi < 4; ++mi) {
        #pragma unroll
        for (int ni = 0; ni < 4; ++ni) {
            const int col = wc + ni * 16 + (lane & 15);
            #pragma unroll
            for (int r = 0; r < 4; ++r) {
                const int row = wr + mi * 16 + (lane >> 4) * 4 + r;
                Hlds[row * 128 + ((((col >> 3) ^ (row & 7)) << 3) | (col & 7))]
                    = f2bf(fmaxf(acc[mi][ni][r], 0.f));
            }
        }
    }
    __syncthreads();

    // 2) P[128,16] = H_tile @ V_slice^T via 8 MFMAs; wave handles 2 m-frags
    const int kb0 = bn >> 5;                   // first 32-wide k-frag of this bn
    bf16x8 vb[4];
    #pragma unroll
    for (int kk = 0; kk < 4; ++kk)
        vb[kk] = *(const bf16x8*)&Vfrag[(kb0 + kk) * 512 + lane * 8];

    #pragma unroll
    for (int mf = 0; mf < 2; ++mf) {
        const int mloc = (wid * 2 + mf) * 16;  // m-frag base row (0..112)
        const int mrow = mloc + (lane & 15);
        f32x4 pac = {};
        #pragma unroll
        for (int kk = 0; kk < 4; ++kk) {
            const int slot = kk * 4 + (lane >> 4);
            bf16x8 ha = *(const bf16x8*)&Hlds[mrow * 128 + ((slot ^ (mrow & 7)) << 3)];
            pac = __builtin_amdgcn_mfma_f32_16x16x32_bf16(ha, vb[kk], pac, 0, 0, 0);
        }
        const int o = lane & 15;
        if (o < OD) {
            #pragma unroll
            for (int r = 0; r < 4; ++r) {
                const int rowg = bm + mloc + (lane >> 4) * 4 + r;
                atomicAdd(&out[(size_t)rowg * OD + o], pac[r]);
            }
        }
    }
}

// ================= fallback (round-1 f32 SIMT fused kernel) ================
#define BM 128
#define BN 128
#define BK 16
__global__ __launch_bounds__(256, 2) void fused_tilednn(
    const float* __restrict__ x, const int* __restrict__ tile1,
    const float* __restrict__ alphas1, const int* __restrict__ tile2,
    const float* __restrict__ alphas2, float* __restrict__ out)
{
    __shared__ float XsF[BK][BM];
    __shared__ float SsF[BK][BN];
    __shared__ float Vl[OD][BN];
    const int t = threadIdx.x, tx = t & 15, ty = t >> 4;
    const int bm = blockIdx.x * BM, bn = blockIdx.y * BN;
    for (int e = t; e < OD * BN; e += 256) {
        const int o = e / BN, rl = e - o * BN, rr = bn + rl;
        float v = 0.f;
        #pragma unroll
        for (int c = 0; c < 4; ++c) {
            const int idx = o * HID + c * RP + rr;
            const int ch = idx / TS2;
            v = fmaf(alphas1[c], alphas2[ch] * (float)(2 * tile2[idx - ch * TS2] - 1), v);
        }
        Vl[o][rl] = v;
    }
    float acc[8][8];
    #pragma unroll
    for (int i = 0; i < 8; ++i)
        #pragma unroll
        for (int j = 0; j < 8; ++j) acc[i][j] = 0.f;
    const int lr = t >> 1, lk = (t & 1) << 3;
    const float* xrow = x + (size_t)(bm + lr) * K_;
    const int* srow = tile1 + (size_t)(bn + lr) * K_;
    for (int k0 = 0; k0 < K_; k0 += BK) {
        __syncthreads();
        const float4 xa = *(const float4*)(xrow + k0 + lk);
        const float4 xb = *(const float4*)(xrow + k0 + lk + 4);
        const int4 sa = *(const int4*)(srow + k0 + lk);
        const int4 sb = *(const int4*)(srow + k0 + lk + 4);
        XsF[lk+0][lr]=xa.x; XsF[lk+1][lr]=xa.y; XsF[lk+2][lr]=xa.z; XsF[lk+3][lr]=xa.w;
        XsF[lk+4][lr]=xb.x; XsF[lk+5][lr]=xb.y; XsF[lk+6][lr]=xb.z; XsF[lk+7][lr]=xb.w;
        SsF[lk+0][lr]=(float)(2*sa.x-1); SsF[lk+1][lr]=(float)(2*sa.y-1);
        SsF[lk+2][lr]=(float)(2*sa.z-1); SsF[lk+3][lr]=(float)(2*sa.w-1);
        SsF[lk+4][lr]=(float)(2*sb.x-1); SsF[lk+5][lr]=(float)(2*sb.y-1);
        SsF[lk+6][lr]=(float)(2*sb.z-1); SsF[lk+7][lr]=(float)(2*sb.w-1);
        __syncthreads();
        #pragma unroll
        for (int k = 0; k < BK; ++k) {
            float av[8], bv[8];
            #pragma unroll
            for (int i = 0; i < 8; ++i) av[i] = XsF[k][ty*8+i];
            #pragma unroll
            for (int j = 0; j < 8; ++j) bv[j] = SsF[k][tx*8+j];
            #pragma unroll
            for (int i = 0; i < 8; ++i)
                #pragma unroll
                for (int j = 0; j < 8; ++j) acc[i][j] = fmaf(av[i], bv[j], acc[i][j]);
        }
    }
    #pragma unroll
    for (int i = 0; i < 8; ++i)
        #pragma unroll
        for (int j = 0; j < 8; ++j) acc[i][j] = fmaxf(acc[i][j], 0.f);
    #pragma unroll
    for (int o = 0; o < OD; ++o) {
        float vv[8];
        #pragma unroll
        for (int j = 0; j < 8; ++j) vv[j] = Vl[o][tx*8+j];
        float p[8];
        #pragma unroll
        for (int i = 0; i < 8; ++i) {
            float s = 0.f;
            #pragma unroll
            for (int j = 0; j < 8; ++j) s = fmaf(acc[i][j], vv[j], s);
            p[i] = s;
        }
        #pragma unroll
        for (int m = 8; m >= 1; m >>= 1)
            #pragma unroll
            for (int i = 0; i < 8; ++i) p[i] += __shfl_xor(p[i], m, 16);
        if (tx == 0) {
            #pragma unroll
            for (int i = 0; i < 8; ++i)
                atomicAdd(&out[(size_t)(bm + ty*8 + i) * OD + o], p[i]);
        }
    }
}

// ================= launch ==================================================
extern "C" void kernel_launch(void* const* d_in, const int* in_sizes, int n_in,
                              void* d_out, int out_size, void* d_ws, size_t ws_size,
                              hipStream_t stream) {
    const float* x       = (const float*)d_in[0];
    const int*   tile1   = (const int*)  d_in[1];
    const float* alphas1 = (const float*)d_in[2];
    const int*   tile2   = (const int*)  d_in[3];
    const float* alphas2 = (const float*)d_in[4];
    float*       out     = (float*)d_out;

    const size_t OFF_X = 0;                                   // 8192*832*2
    const size_t OFF_S = OFF_X + (size_t)B_ * KP * 2;         // + 1024*832*2
    const size_t OFF_F = OFF_S + (size_t)RP * KP * 2;         // + 16*1024*2
    const size_t NEED  = OFF_F + (size_t)16 * RP * 2;         // ~15.4 MB

    if (ws_size < NEED) {
        hipMemsetAsync(out, 0, (size_t)out_size * sizeof(float), stream);
        dim3 grid(B_ / BM, RP / BN);
        fused_tilednn<<<grid, 256, 0, stream>>>(x, tile1, alphas1, tile2, alphas2, out);
        return;
    }

    unsigned short* Xsw   = (unsigned short*)((char*)d_ws + OFF_X);
    unsigned short* Sfrag = (unsigned short*)((char*)d_ws + OFF_S);
    unsigned short* Vfrag = (unsigned short*)((char*)d_ws + OFF_F);

    prep<<<NB_X + NB_S + NB_F + NB_Z, 256, 0, stream>>>(
        x, tile1, tile2, alphas1, alphas2, Xsw, Sfrag, Vfrag, out);
    gemm1<<<512, 256, 0, stream>>>(Xsw, Sfrag, Vfrag, out);
}

// Round 9
// 28.021 us; speedup vs baseline: 1.3016x; 1.3016x over previous
//
#include <hip/hip_runtime.h>

// ---------------- problem constants ----------------
#define B_    8192
#define K_    784      // IN_DIM
#define KP    832      // K padded to 13*64
#define NKB   13       // K blocks of 64 (one mfma_i32_16x16x64 per block)
#define RP    1024     // unique w1 rows = HIDDEN/CF
#define HID   4096
#define OD    10
#define TS2   10240    // OUT_DIM*HIDDEN/CF

#define NB_XQ 1664     // 8192*52/256  (x -> i8)
#define NB_SQ 208      // 1024*52/256  (tile1 -> +/-1 i8)
#define NB_F  64       // 16*1024/256  (Vfrag bf16)
#define NB_Z  80       // 80*256*4 = 81920 floats of out zeroing

typedef __attribute__((ext_vector_type(8))) short  bf16x8;
typedef __attribute__((ext_vector_type(4))) int    i32x4;
typedef __attribute__((ext_vector_type(4))) float  f32x4;

__device__ __forceinline__ unsigned short f2bf(float f) {
    unsigned u = __builtin_bit_cast(unsigned, f);
    u += 0x7fffu + ((u >> 16) & 1u);          // RNE
    return (unsigned short)(u >> 16);
}
__device__ __forceinline__ int qz32(float v) {  // q = rint(clamp(32x))
    v = fminf(fmaxf(v * 32.f, -127.f), 127.f);
    return (int)__builtin_rintf(v);
}

// ================= merged prep kernel =====================================
// i8 operand layout (both X and S): Arr[row][kb][s][e] (bytes, row stride 832)
//   = src[row][kb*64 + (s ^ xi(row))*16 + e],  xi(row) = (row>>1)&3,
//   zero beyond col 784. 16B slots; XOR swizzle -> 2-way max on frag reads.
// blocks [0, NB_XQ)  : x -> i8, q = rint(32*x) clamped (exact pow2 scale)
// blocks [.., +NB_SQ): tile1 -> +1/-1 i8
// blocks [.., +NB_F) : Vfrag (bf16, MFMA B-fragment order, o padded to 16)
// blocks [.., +NB_Z) : zero out[]
__global__ __launch_bounds__(256) void prep(
    const float* __restrict__ x, const int* __restrict__ t1,
    const int* __restrict__ t2, const float* __restrict__ a1,
    const float* __restrict__ a2,
    signed char* __restrict__ Xq, signed char* __restrict__ Sq,
    unsigned short* __restrict__ Vfrag, float* __restrict__ out)
{
    const int b = blockIdx.x;
    if (b < NB_XQ) {
        const int id  = b * 256 + threadIdx.x;      // < 8192*52
        const int row = id / 52;
        const int rem = id - row * 52;
        const int kb  = rem >> 2;                   // 0..12
        const int s   = rem & 3;
        const int xi  = (row >> 1) & 3;
        const int k0  = kb * 64 + ((s ^ xi) << 4);
        i32x4 w = {0, 0, 0, 0};
        if (k0 < K_) {                              // 784 % 16 == 0: all-or-none
            const float* xp = x + (size_t)row * K_ + k0;
            #pragma unroll
            for (int g = 0; g < 4; ++g) {
                f32x4 a = *(const f32x4*)(xp + g * 4);
                const int q0 = qz32(a.x), q1 = qz32(a.y);
                const int q2 = qz32(a.z), q3 = qz32(a.w);
                w[g] = (q0 & 255) | ((q1 & 255) << 8) |
                       ((q2 & 255) << 16) | ((q3 & 255) << 24);
            }
        }
        *(i32x4*)(Xq + (size_t)row * KP + kb * 64 + s * 16) = w;
    } else if (b < NB_XQ + NB_SQ) {
        const int id  = (b - NB_XQ) * 256 + threadIdx.x;   // < 1024*52
        const int row = id / 52;
        const int rem = id - row * 52;
        const int kb  = rem >> 2;
        const int s   = rem & 3;
        const int xi  = (row >> 1) & 3;
        const int k0  = kb * 64 + ((s ^ xi) << 4);
        i32x4 w = {0, 0, 0, 0};
        if (k0 < K_) {
            const int* tp = t1 + (size_t)row * K_ + k0;
            #pragma unroll
            for (int g = 0; g < 4; ++g) {
                int wg = 0;
                #pragma unroll
                for (int j = 0; j < 4; ++j)
                    wg |= (tp[g * 4 + j] ? 0x01 : 0xFF) << (8 * j);
                w[g] = wg;
            }
        }
        *(i32x4*)(Sq + (size_t)row * KP + kb * 64 + s * 16) = w;
    } else if (b < NB_XQ + NB_SQ + NB_F) {
        const int id = (b - NB_XQ - NB_SQ) * 256 + threadIdx.x;   // < 16384
        const int o = id >> 10;           // 0..15 (10..15 are zero pad)
        const int r = id & 1023;
        float v = 0.f;
        if (o < OD) {
            #pragma unroll
            for (int c = 0; c < 4; ++c) {
                const int idx = o * HID + c * RP + r;
                const int ch  = idx / TS2;
                const float w2v = a2[ch] * (float)(2 * t2[idx - ch * TS2] - 1);
                v = fmaf(a1[c], w2v, v);
            }
        }
        Vfrag[(r >> 5) * 512 + (o + 16 * ((r >> 3) & 3)) * 8 + (r & 7)] = f2bf(v);
    } else {
        const int id = (b - NB_XQ - NB_SQ - NB_F) * 256 + threadIdx.x;
        ((f32x4*)out)[id] = (f32x4){0.f, 0.f, 0.f, 0.f};
    }
}

// ================= GEMM1 (i8) + fused layer 2 =============================
// Round-6 structure, i8 operands: 128x128 tile, BK=64 single-buffered
// (A 8KB + B 8KB LDS), 2 syncthreads/step, 4 waves 2x2, one
// mfma_i32_16x16x64_i8 per frag-pair per step (16/wave). 512 blocks,
// XCD-chunked. Exact i32 accumulate; dequant h = acc * 2^-5.
// Epilogue: relu->bf16->Hlds overlay, bf16 mini-GEMM vs Vfrag, atomicAdd.
__global__ __launch_bounds__(256, 3) void gemm1(const signed char* __restrict__ Xq,
                                                const signed char* __restrict__ Sq,
                                                const unsigned short* __restrict__ Vfrag,
                                                float* __restrict__ out) {
    __shared__ unsigned char SH[32768];   // loop: [0,8K)=A, [8K,16K)=B; then Hlds

    const int tid  = threadIdx.x;
    const int lane = tid & 63;
    const int wid  = tid >> 6;

    // bijective XCD-chunked swizzle: XCD k owns bm-tiles [8k, 8k+8) x all bn
    const int swz = (blockIdx.x & 7) * 64 + (blockIdx.x >> 3);
    const int bm  = (swz >> 3) * 128;
    const int bn  = (swz & 7) * 128;

    const int wr = (wid >> 1) * 64;
    const int wc = (wid & 1) * 64;

    // staging lane constants: per iter a wave copies 16 rows x 64B (1KB)
    const int srow = lane >> 2;                  // 0..15 row within chunk
    const int sslt = (lane & 3) << 4;            // byte slot offset in 64B row

    // fragment-read lane constants
    const int kg = lane >> 4;                                  // 0..3
    const int xr = ((lane & 15) >> 1) & 3;                     // xi of frag row
    const int fsl = (kg ^ xr) << 4;                            // phys slot bytes
    const int frow = lane & 15;

    i32x4 acc[4][4] = {};

    for (int kb = 0; kb < NKB; ++kb) {
        // ---- stage A (8KB) + B (8KB): 2+2 gload_lds per wave ----
        #pragma unroll
        for (int i = 0; i < 2; ++i) {
            const int base = wid * 2048 + i * 1024;         // bytes in 8KB tile
            const int row  = (base >> 6) + srow;            // 0..127
            const signed char* ga = Xq + (size_t)(bm + row) * KP + kb * 64 + sslt;
            const signed char* gb = Sq + (size_t)(bn + row) * KP + kb * 64 + sslt;
            __builtin_amdgcn_global_load_lds(
                (const __attribute__((address_space(1))) void*)ga,
                (__attribute__((address_space(3))) void*)(&SH[base + lane * 16]),
                16, 0, 0);
            __builtin_amdgcn_global_load_lds(
                (const __attribute__((address_space(1))) void*)gb,
                (__attribute__((address_space(3))) void*)(&SH[8192 + base + lane * 16]),
                16, 0, 0);
        }
        __syncthreads();                       // loads landed (vmcnt drain)

        i32x4 af[4], bfr[4];
        #pragma unroll
        for (int mi = 0; mi < 4; ++mi)
            af[mi] = *(const i32x4*)&SH[(wr + mi * 16 + frow) * 64 + fsl];
        #pragma unroll
        for (int ni = 0; ni < 4; ++ni)
            bfr[ni] = *(const i32x4*)&SH[8192 + (wc + ni * 16 + frow) * 64 + fsl];
        #pragma unroll
        for (int mi = 0; mi < 4; ++mi)
            #pragma unroll
            for (int ni = 0; ni < 4; ++ni)
                acc[mi][ni] = __builtin_amdgcn_mfma_i32_16x16x64_i8(
                    af[mi], bfr[ni], acc[mi][ni], 0, 0, 0);

        __syncthreads();                       // all reads done before restage
    }

    // ---- fused epilogue ----------------------------------------------------
    // 1) dequant + relu -> bf16 -> Hlds[128][128] (col-slot XOR swizzle)
    unsigned short* Hlds = (unsigned short*)SH;   // 128*128 ushorts = 32 KB
    #pragma unroll
    for (int mi = 0; mi < 4; ++mi) {
        #pragma unroll
        for (int ni = 0; ni < 4; ++ni) {
            const int col = wc + ni * 16 + (lane & 15);
            #pragma unroll
            for (int r = 0; r < 4; ++r) {
                const int row = wr + mi * 16 + (lane >> 4) * 4 + r;
                const float hv = (float)acc[mi][ni][r] * 0.03125f;   // /32 exact
                Hlds[row * 128 + ((((col >> 3) ^ (row & 7)) << 3) | (col & 7))]
                    = f2bf(fmaxf(hv, 0.f));
            }
        }
    }
    __syncthreads();

    // 2) P[128,16] = H_tile @ V_slice^T via 8 MFMAs; wave handles 2 m-frags
    const int kb0 = bn >> 5;                   // first 32-wide k-frag of this bn
    bf16x8 vb[4];
    #pragma unroll
    for (int kk = 0; kk < 4; ++kk)
        vb[kk] = *(const bf16x8*)&Vfrag[(kb0 + kk) * 512 + lane * 8];

    #pragma unroll
    for (int mf = 0; mf < 2; ++mf) {
        const int mloc = (wid * 2 + mf) * 16;  // m-frag base row (0..112)
        const int mrow = mloc + (lane & 15);
        f32x4 pac = {};
        #pragma unroll
        for (int kk = 0; kk < 4; ++kk) {
            const int slot = kk * 4 + (lane >> 4);
            bf16x8 ha = *(const bf16x8*)&Hlds[mrow * 128 + ((slot ^ (mrow & 7)) << 3)];
            pac = __builtin_amdgcn_mfma_f32_16x16x32_bf16(ha, vb[kk], pac, 0, 0, 0);
        }
        const int o = lane & 15;
        if (o < OD) {
            #pragma unroll
            for (int r = 0; r < 4; ++r) {
                const int rowg = bm + mloc + (lane >> 4) * 4 + r;
                atomicAdd(&out[(size_t)rowg * OD + o], pac[r]);
            }
        }
    }
}

// ================= fallback (round-1 f32 SIMT fused kernel) ================
#define BM 128
#define BN 128
#define BK 16
__global__ __launch_bounds__(256, 2) void fused_tilednn(
    const float* __restrict__ x, const int* __restrict__ tile1,
    const float* __restrict__ alphas1, const int* __restrict__ tile2,
    const float* __restrict__ alphas2, float* __restrict__ out)
{
    __shared__ float XsF[BK][BM];
    __shared__ float SsF[BK][BN];
    __shared__ float Vl[OD][BN];
    const int t = threadIdx.x, tx = t & 15, ty = t >> 4;
    const int bm = blockIdx.x * BM, bn = blockIdx.y * BN;
    for (int e = t; e < OD * BN; e += 256) {
        const int o = e / BN, rl = e - o * BN, rr = bn + rl;
        float v = 0.f;
        #pragma unroll
        for (int c = 0; c < 4; ++c) {
            const int idx = o * HID + c * RP + rr;
            const int ch = idx / TS2;
            v = fmaf(alphas1[c], alphas2[ch] * (float)(2 * tile2[idx - ch * TS2] - 1), v);
        }
        Vl[o][rl] = v;
    }
    float acc[8][8];
    #pragma unroll
    for (int i = 0; i < 8; ++i)
        #pragma unroll
        for (int j = 0; j < 8; ++j) acc[i][j] = 0.f;
    const int lr = t >> 1, lk = (t & 1) << 3;
    const float* xrow = x + (size_t)(bm + lr) * K_;
    const int* srow = tile1 + (size_t)(bn + lr) * K_;
    for (int k0 = 0; k0 < K_; k0 += BK) {
        __syncthreads();
        const float4 xa = *(const float4*)(xrow + k0 + lk);
        const float4 xb = *(const float4*)(xrow + k0 + lk + 4);
        const int4 sa = *(const int4*)(srow + k0 + lk);
        const int4 sb = *(const int4*)(srow + k0 + lk + 4);
        XsF[lk+0][lr]=xa.x; XsF[lk+1][lr]=xa.y; XsF[lk+2][lr]=xa.z; XsF[lk+3][lr]=xa.w;
        XsF[lk+4][lr]=xb.x; XsF[lk+5][lr]=xb.y; XsF[lk+6][lr]=xb.z; XsF[lk+7][lr]=xb.w;
        SsF[lk+0][lr]=(float)(2*sa.x-1); SsF[lk+1][lr]=(float)(2*sa.y-1);
        SsF[lk+2][lr]=(float)(2*sa.z-1); SsF[lk+3][lr]=(float)(2*sa.w-1);
        SsF[lk+4][lr]=(float)(2*sb.x-1); SsF[lk+5][lr]=(float)(2*sb.y-1);
        SsF[lk+6][lr]=(float)(2*sb.z-1); SsF[lk+7][lr]=(float)(2*sb.w-1);
        __syncthreads();
        #pragma unroll
        for (int k = 0; k < BK; ++k) {
            float av[8], bv[8];
            #pragma unroll
            for (int i = 0; i < 8; ++i) av[i] = XsF[k][ty*8+i];
            #pragma unroll
            for (int j = 0; j < 8; ++j) bv[j] = SsF[k][tx*8+j];
            #pragma unroll
            for (int i = 0; i < 8; ++i)
                #pragma unroll
                for (int j = 0; j < 8; ++j) acc[i][j] = fmaf(av[i], bv[j], acc[i][j]);
        }
    }
    #pragma unroll
    for (int i = 0; i < 8; ++i)
        #pragma unroll
        for (int j = 0; j < 8; ++j) acc[i][j] = fmaxf(acc[i][j], 0.f);
    #pragma unroll
    for (int o = 0; o < OD; ++o) {
        float vv[8];
        #pragma unroll
        for (int j = 0; j < 8; ++j) vv[j] = Vl[o][tx*8+j];
        float p[8];
        #pragma unroll
        for (int i = 0; i < 8; ++i) {
            float s = 0.f;
            #pragma unroll
            for (int j = 0; j < 8; ++j) s = fmaf(acc[i][j], vv[j], s);
            p[i] = s;
        }
        #pragma unroll
        for (int m = 8; m >= 1; m >>= 1)
            #pragma unroll
            for (int i = 0; i < 8; ++i) p[i] += __shfl_xor(p[i], m, 16);
        if (tx == 0) {
            #pragma unroll
            for (int i = 0; i < 8; ++i)
                atomicAdd(&out[(size_t)(bm + ty*8 + i) * OD + o], p[i]);
        }
    }
}

// ================= launch ==================================================
extern "C" void kernel_launch(void* const* d_in, const int* in_sizes, int n_in,
                              void* d_out, int out_size, void* d_ws, size_t ws_size,
                              hipStream_t stream) {
    const float* x       = (const float*)d_in[0];
    const int*   tile1   = (const int*)  d_in[1];
    const float* alphas1 = (const float*)d_in[2];
    const int*   tile2   = (const int*)  d_in[3];
    const float* alphas2 = (const float*)d_in[4];
    float*       out     = (float*)d_out;

    const size_t OFF_XQ = 0;                                  // 8192*832
    const size_t OFF_SQ = OFF_XQ + (size_t)B_ * KP;           // + 1024*832
    const size_t OFF_F  = OFF_SQ + (size_t)RP * KP;           // + 16*1024*2
    const size_t NEED   = OFF_F + (size_t)16 * RP * 2;        // ~7.7 MB

    if (ws_size < NEED) {
        hipMemsetAsync(out, 0, (size_t)out_size * sizeof(float), stream);
        dim3 grid(B_ / BM, RP / BN);
        fused_tilednn<<<grid, 256, 0, stream>>>(x, tile1, alphas1, tile2, alphas2, out);
        return;
    }

    signed char*    Xq    = (signed char*)((char*)d_ws + OFF_XQ);
    signed char*    Sq    = (signed char*)((char*)d_ws + OFF_SQ);
    unsigned short* Vfrag = (unsigned short*)((char*)d_ws + OFF_F);

    prep<<<NB_XQ + NB_SQ + NB_F + NB_Z, 256, 0, stream>>>(
        x, tile1, tile2, alphas1, alphas2, Xq, Sq, Vfrag, out);
    gemm1<<<512, 256, 0, stream>>>(Xq, Sq, Vfrag, out);
}

// Round 10
// 25.383 us; speedup vs baseline: 1.4369x; 1.1039x over previous
//
#include <hip/hip_runtime.h>

// ---------------- problem constants ----------------
#define B_    8192
#define K_    784      // IN_DIM
#define KP    896      // K padded to 7*128 (i8 bytes per row)
#define NKT   7        // K tiles of 128 (2 x mfma_i32_16x16x64 per tile)
#define RP    1024     // unique w1 rows = HIDDEN/CF
#define HID   4096
#define OD    10
#define TS2   10240    // OUT_DIM*HIDDEN/CF

#define NB_XQ 1792     // 8192*56/256  (x -> i8)
#define NB_SQ 224      // 1024*56/256  (tile1 -> +/-1 i8)
#define NB_F  64       // 16*1024/256  (Vfrag bf16)
#define NB_Z  80       // 80*256*4 = 81920 floats of out zeroing

typedef __attribute__((ext_vector_type(8))) short  bf16x8;
typedef __attribute__((ext_vector_type(4))) int    i32x4;
typedef __attribute__((ext_vector_type(4))) float  f32x4;

__device__ __forceinline__ unsigned short f2bf(float f) {
    unsigned u = __builtin_bit_cast(unsigned, f);
    u += 0x7fffu + ((u >> 16) & 1u);          // RNE
    return (unsigned short)(u >> 16);
}
__device__ __forceinline__ int qz32(float v) {  // q = rint(clamp(32x))
    v = fminf(fmaxf(v * 32.f, -127.f), 127.f);
    return (int)__builtin_rintf(v);
}

// ================= merged prep kernel =====================================
// i8 operand layout (X and S): Arr[row][kb][s][e] (bytes, row stride 896)
//   = src[row][kb*64 + (s ^ xi(row))*16 + e],  xi(row) = (row>>1)&3,
//   zero beyond col 784 (784%16==0 -> all-or-none per 16B slot).
// blocks [0, NB_XQ)  : x -> i8, q = rint(32*x) clamped (exact pow2 scale)
// blocks [.., +NB_SQ): tile1 -> +1/-1 i8
// blocks [.., +NB_F) : Vfrag (bf16, MFMA B-fragment order, o padded to 16)
// blocks [.., +NB_Z) : zero out[]
__global__ __launch_bounds__(256) void prep(
    const float* __restrict__ x, const int* __restrict__ t1,
    const int* __restrict__ t2, const float* __restrict__ a1,
    const float* __restrict__ a2,
    signed char* __restrict__ Xq, signed char* __restrict__ Sq,
    unsigned short* __restrict__ Vfrag, float* __restrict__ out)
{
    const int b = blockIdx.x;
    if (b < NB_XQ) {
        const int id  = b * 256 + threadIdx.x;      // < 8192*56
        const int row = id / 56;
        const int rem = id - row * 56;
        const int kb  = rem >> 2;                   // 0..13
        const int s   = rem & 3;
        const int xi  = (row >> 1) & 3;
        const int k0  = kb * 64 + ((s ^ xi) << 4);
        i32x4 w = {0, 0, 0, 0};
        if (k0 < K_) {
            const float* xp = x + (size_t)row * K_ + k0;
            #pragma unroll
            for (int g = 0; g < 4; ++g) {
                f32x4 a = *(const f32x4*)(xp + g * 4);
                const int q0 = qz32(a.x), q1 = qz32(a.y);
                const int q2 = qz32(a.z), q3 = qz32(a.w);
                w[g] = (q0 & 255) | ((q1 & 255) << 8) |
                       ((q2 & 255) << 16) | ((q3 & 255) << 24);
            }
        }
        *(i32x4*)(Xq + (size_t)row * KP + kb * 64 + s * 16) = w;
    } else if (b < NB_XQ + NB_SQ) {
        const int id  = (b - NB_XQ) * 256 + threadIdx.x;   // < 1024*56
        const int row = id / 56;
        const int rem = id - row * 56;
        const int kb  = rem >> 2;
        const int s   = rem & 3;
        const int xi  = (row >> 1) & 3;
        const int k0  = kb * 64 + ((s ^ xi) << 4);
        i32x4 w = {0, 0, 0, 0};
        if (k0 < K_) {
            const int* tp = t1 + (size_t)row * K_ + k0;
            #pragma unroll
            for (int g = 0; g < 4; ++g) {
                int wg = 0;
                #pragma unroll
                for (int j = 0; j < 4; ++j)
                    wg |= (tp[g * 4 + j] ? 0x01 : 0xFF) << (8 * j);
                w[g] = wg;
            }
        }
        *(i32x4*)(Sq + (size_t)row * KP + kb * 64 + s * 16) = w;
    } else if (b < NB_XQ + NB_SQ + NB_F) {
        const int id = (b - NB_XQ - NB_SQ) * 256 + threadIdx.x;   // < 16384
        const int o = id >> 10;           // 0..15 (10..15 are zero pad)
        const int r = id & 1023;
        float v = 0.f;
        if (o < OD) {
            #pragma unroll
            for (int c = 0; c < 4; ++c) {
                const int idx = o * HID + c * RP + r;
                const int ch  = idx / TS2;
                const float w2v = a2[ch] * (float)(2 * t2[idx - ch * TS2] - 1);
                v = fmaf(a1[c], w2v, v);
            }
        }
        Vfrag[(r >> 5) * 512 + (o + 16 * ((r >> 3) & 3)) * 8 + (r & 7)] = f2bf(v);
    } else {
        const int id = (b - NB_XQ - NB_SQ - NB_F) * 256 + threadIdx.x;
        ((f32x4*)out)[id] = (f32x4){0.f, 0.f, 0.f, 0.f};
    }
}

// ================= GEMM1 (i8) + fused layer 2 =============================
// 128x128 tile, BK=128 bytes (2 i8 K-blocks per step, 7 steps), double-
// buffered 64 KB LDS, 1-deep prefetch with counted vmcnt + raw barriers
// (round-3 proven pipeline), 4 waves 2x2, 512 blocks XCD-chunked = 2/CU.
// Exact i32 accumulate; dequant h = acc * 2^-5.
// Epilogue: relu->bf16->Hlds overlay, bf16 mini-GEMM vs Vfrag, atomicAdd.
__global__ __launch_bounds__(256, 2) void gemm1(const signed char* __restrict__ Xq,
                                                const signed char* __restrict__ Sq,
                                                const unsigned short* __restrict__ Vfrag,
                                                float* __restrict__ out) {
    __shared__ unsigned char SH[65536];   // 2 bufs x {A even 8K | A odd 8K | B even 8K | B odd 8K}

    const int tid  = threadIdx.x;
    const int lane = tid & 63;
    const int wid  = tid >> 6;

    // bijective XCD-chunked swizzle: XCD k owns bm-tiles [8k, 8k+8) x all bn
    const int swz = (blockIdx.x & 7) * 64 + (blockIdx.x >> 3);
    const int bm  = (swz >> 3) * 128;
    const int bn  = (swz & 7) * 128;

    const int wr = (wid >> 1) * 64;
    const int wc = (wid & 1) * 64;

    // staging lane constants: per 1KB gload chunk a wave covers 16 rows x 64B
    const int srow = lane >> 2;                  // 0..15 row within chunk
    const int sslt = (lane & 3) << 4;            // byte slot offset in 64B row

    // fragment-read lane constants
    const int kg   = lane >> 4;                  // 0..3 k-group
    const int xr   = ((lane & 15) >> 1) & 3;     // xi of frag row
    const int fsl  = (kg ^ xr) << 4;             // physical slot bytes
    const int frow = lane & 15;

    i32x4 acc[4][4] = {};

    // stage K-tile T (bytes [T*128, T*128+128) of each row) into buffer BUF
#define STAGE(T, BUF)                                                           \
    do {                                                                        \
        _Pragma("unroll")                                                       \
        for (int i = 0; i < 2; ++i) {                                           \
            const int base = wid * 2048 + i * 1024;                             \
            const int row  = wid * 32 + i * 16 + srow;                          \
            const signed char* ga = Xq + (size_t)(bm + row) * KP + (T) * 128 + sslt; \
            const signed char* gb = Sq + (size_t)(bn + row) * KP + (T) * 128 + sslt; \
            __builtin_amdgcn_global_load_lds(                                   \
                (const __attribute__((address_space(1))) void*)ga,              \
                (__attribute__((address_space(3))) void*)                       \
                    (&SH[(BUF) * 32768 + base + lane * 16]), 16, 0, 0);         \
            __builtin_amdgcn_global_load_lds(                                   \
                (const __attribute__((address_space(1))) void*)(ga + 64),       \
                (__attribute__((address_space(3))) void*)                       \
                    (&SH[(BUF) * 32768 + 8192 + base + lane * 16]), 16, 0, 0);  \
            __builtin_amdgcn_global_load_lds(                                   \
                (const __attribute__((address_space(1))) void*)gb,              \
                (__attribute__((address_space(3))) void*)                       \
                    (&SH[(BUF) * 32768 + 16384 + base + lane * 16]), 16, 0, 0); \
            __builtin_amdgcn_global_load_lds(                                   \
                (const __attribute__((address_space(1))) void*)(gb + 64),       \
                (__attribute__((address_space(3))) void*)                       \
                    (&SH[(BUF) * 32768 + 24576 + base + lane * 16]), 16, 0, 0); \
        }                                                                       \
    } while (0)

#define COMPUTE(BUF)                                                            \
    do {                                                                        \
        _Pragma("unroll")                                                       \
        for (int half = 0; half < 2; ++half) {                                  \
            i32x4 af[4], bfr[4];                                                \
            _Pragma("unroll")                                                   \
            for (int mi = 0; mi < 4; ++mi)                                      \
                af[mi] = *(const i32x4*)&SH[(BUF) * 32768 + half * 8192         \
                                            + (wr + mi * 16 + frow) * 64 + fsl];\
            _Pragma("unroll")                                                   \
            for (int ni = 0; ni < 4; ++ni)                                      \
                bfr[ni] = *(const i32x4*)&SH[(BUF) * 32768 + 16384 + half * 8192\
                                             + (wc + ni * 16 + frow) * 64 + fsl];\
            _Pragma("unroll")                                                   \
            for (int mi = 0; mi < 4; ++mi)                                      \
                _Pragma("unroll")                                               \
                for (int ni = 0; ni < 4; ++ni)                                  \
                    acc[mi][ni] = __builtin_amdgcn_mfma_i32_16x16x64_i8(        \
                        af[mi], bfr[ni], acc[mi][ni], 0, 0, 0);                 \
        }                                                                       \
    } while (0)

    STAGE(0, 0);                                 // prologue: 8 loads in flight

    for (int t = 0; t < NKT; ++t) {
        const int cur = t & 1;
        if (t + 1 < NKT) {
            STAGE(t + 1, cur ^ 1);               // +8 loads (16 outstanding)
            asm volatile("s_waitcnt vmcnt(8)" ::: "memory");  // tile t landed
        } else {
            asm volatile("s_waitcnt vmcnt(0)" ::: "memory");
        }
        __builtin_amdgcn_s_barrier();            // raw: does NOT drain vmcnt
        __builtin_amdgcn_sched_barrier(0);
        COMPUTE(cur);
        __builtin_amdgcn_sched_barrier(0);
        __builtin_amdgcn_s_barrier();            // all done reading cur buffer
    }
#undef STAGE
#undef COMPUTE

    // ---- fused epilogue ----------------------------------------------------
    // 1) dequant + relu -> bf16 -> Hlds[128][128] (col-slot XOR swizzle)
    unsigned short* Hlds = (unsigned short*)SH;   // 128*128 ushorts = 32 KB
    __syncthreads();                              // all SH reads complete
    #pragma unroll
    for (int mi = 0; mi < 4; ++mi) {
        #pragma unroll
        for (int ni = 0; ni < 4; ++ni) {
            const int col = wc + ni * 16 + (lane & 15);
            #pragma unroll
            for (int r = 0; r < 4; ++r) {
                const int row = wr + mi * 16 + (lane >> 4) * 4 + r;
                const float hv = (float)acc[mi][ni][r] * 0.03125f;   // /32 exact
                Hlds[row * 128 + ((((col >> 3) ^ (row & 7)) << 3) | (col & 7))]
                    = f2bf(fmaxf(hv, 0.f));
            }
        }
    }
    __syncthreads();

    // 2) P[128,16] = H_tile @ V_slice^T via 8 MFMAs; wave handles 2 m-frags
    const int kb0 = bn >> 5;                   // first 32-wide k-frag of this bn
    bf16x8 vb[4];
    #pragma unroll
    for (int kk = 0; kk < 4; ++kk)
        vb[kk] = *(const bf16x8*)&Vfrag[(kb0 + kk) * 512 + lane * 8];

    #pragma unroll
    for (int mf = 0; mf < 2; ++mf) {
        const int mloc = (wid * 2 + mf) * 16;  // m-frag base row (0..112)
        const int mrow = mloc + (lane & 15);
        f32x4 pac = {};
        #pragma unroll
        for (int kk = 0; kk < 4; ++kk) {
            const int slot = kk * 4 + (lane >> 4);
            bf16x8 ha = *(const bf16x8*)&Hlds[mrow * 128 + ((slot ^ (mrow & 7)) << 3)];
            pac = __builtin_amdgcn_mfma_f32_16x16x32_bf16(ha, vb[kk], pac, 0, 0, 0);
        }
        const int o = lane & 15;
        if (o < OD) {
            #pragma unroll
            for (int r = 0; r < 4; ++r) {
                const int rowg = bm + mloc + (lane >> 4) * 4 + r;
                atomicAdd(&out[(size_t)rowg * OD + o], pac[r]);
            }
        }
    }
}

// ================= fallback (round-1 f32 SIMT fused kernel) ================
#define BM 128
#define BN 128
#define BK 16
__global__ __launch_bounds__(256, 2) void fused_tilednn(
    const float* __restrict__ x, const int* __restrict__ tile1,
    const float* __restrict__ alphas1, const int* __restrict__ tile2,
    const float* __restrict__ alphas2, float* __restrict__ out)
{
    __shared__ float XsF[BK][BM];
    __shared__ float SsF[BK][BN];
    __shared__ float Vl[OD][BN];
    const int t = threadIdx.x, tx = t & 15, ty = t >> 4;
    const int bm = blockIdx.x * BM, bn = blockIdx.y * BN;
    for (int e = t; e < OD * BN; e += 256) {
        const int o = e / BN, rl = e - o * BN, rr = bn + rl;
        float v = 0.f;
        #pragma unroll
        for (int c = 0; c < 4; ++c) {
            const int idx = o * HID + c * RP + rr;
            const int ch = idx / TS2;
            v = fmaf(alphas1[c], alphas2[ch] * (float)(2 * tile2[idx - ch * TS2] - 1), v);
        }
        Vl[o][rl] = v;
    }
    float acc[8][8];
    #pragma unroll
    for (int i = 0; i < 8; ++i)
        #pragma unroll
        for (int j = 0; j < 8; ++j) acc[i][j] = 0.f;
    const int lr = t >> 1, lk = (t & 1) << 3;
    const float* xrow = x + (size_t)(bm + lr) * K_;
    const int* srow = tile1 + (size_t)(bn + lr) * K_;
    for (int k0 = 0; k0 < K_; k0 += BK) {
        __syncthreads();
        const float4 xa = *(const float4*)(xrow + k0 + lk);
        const float4 xb = *(const float4*)(xrow + k0 + lk + 4);
        const int4 sa = *(const int4*)(srow + k0 + lk);
        const int4 sb = *(const int4*)(srow + k0 + lk + 4);
        XsF[lk+0][lr]=xa.x; XsF[lk+1][lr]=xa.y; XsF[lk+2][lr]=xa.z; XsF[lk+3][lr]=xa.w;
        XsF[lk+4][lr]=xb.x; XsF[lk+5][lr]=xb.y; XsF[lk+6][lr]=xb.z; XsF[lk+7][lr]=xb.w;
        SsF[lk+0][lr]=(float)(2*sa.x-1); SsF[lk+1][lr]=(float)(2*sa.y-1);
        SsF[lk+2][lr]=(float)(2*sa.z-1); SsF[lk+3][lr]=(float)(2*sa.w-1);
        SsF[lk+4][lr]=(float)(2*sb.x-1); SsF[lk+5][lr]=(float)(2*sb.y-1);
        SsF[lk+6][lr]=(float)(2*sb.z-1); SsF[lk+7][lr]=(float)(2*sb.w-1);
        __syncthreads();
        #pragma unroll
        for (int k = 0; k < BK; ++k) {
            float av[8], bv[8];
            #pragma unroll
            for (int i = 0; i < 8; ++i) av[i] = XsF[k][ty*8+i];
            #pragma unroll
            for (int j = 0; j < 8; ++j) bv[j] = SsF[k][tx*8+j];
            #pragma unroll
            for (int i = 0; i < 8; ++i)
                #pragma unroll
                for (int j = 0; j < 8; ++j) acc[i][j] = fmaf(av[i], bv[j], acc[i][j]);
        }
    }
    #pragma unroll
    for (int i = 0; i < 8; ++i)
        #pragma unroll
        for (int j = 0; j < 8; ++j) acc[i][j] = fmaxf(acc[i][j], 0.f);
    #pragma unroll
    for (int o = 0; o < OD; ++o) {
        float vv[8];
        #pragma unroll
        for (int j = 0; j < 8; ++j) vv[j] = Vl[o][tx*8+j];
        float p[8];
        #pragma unroll
        for (int i = 0; i < 8; ++i) {
            float s = 0.f;
            #pragma unroll
            for (int j = 0; j < 8; ++j) s = fmaf(acc[i][j], vv[j], s);
            p[i] = s;
        }
        #pragma unroll
        for (int m = 8; m >= 1; m >>= 1)
            #pragma unroll
            for (int i = 0; i < 8; ++i) p[i] += __shfl_xor(p[i], m, 16);
        if (tx == 0) {
            #pragma unroll
            for (int i = 0; i < 8; ++i)
                atomicAdd(&out[(size_t)(bm + ty*8 + i) * OD + o], p[i]);
        }
    }
}

// ================= launch ==================================================
extern "C" void kernel_launch(void* const* d_in, const int* in_sizes, int n_in,
                              void* d_out, int out_size, void* d_ws, size_t ws_size,
                              hipStream_t stream) {
    const float* x       = (const float*)d_in[0];
    const int*   tile1   = (const int*)  d_in[1];
    const float* alphas1 = (const float*)d_in[2];
    const int*   tile2   = (const int*)  d_in[3];
    const float* alphas2 = (const float*)d_in[4];
    float*       out     = (float*)d_out;

    const size_t OFF_XQ = 0;                                  // 8192*896
    const size_t OFF_SQ = OFF_XQ + (size_t)B_ * KP;           // + 1024*896
    const size_t OFF_F  = OFF_SQ + (size_t)RP * KP;           // + 16*1024*2
    const size_t NEED   = OFF_F + (size_t)16 * RP * 2;        // ~8.3 MB

    if (ws_size < NEED) {
        hipMemsetAsync(out, 0, (size_t)out_size * sizeof(float), stream);
        dim3 grid(B_ / BM, RP / BN);
        fused_tilednn<<<grid, 256, 0, stream>>>(x, tile1, alphas1, tile2, alphas2, out);
        return;
    }

    signed char*    Xq    = (signed char*)((char*)d_ws + OFF_XQ);
    signed char*    Sq    = (signed char*)((char*)d_ws + OFF_SQ);
    unsigned short* Vfrag = (unsigned short*)((char*)d_ws + OFF_F);

    prep<<<NB_XQ + NB_SQ + NB_F + NB_Z, 256, 0, stream>>>(
        x, tile1, tile2, alphas1, alphas2, Xq, Sq, Vfrag, out);
    gemm1<<<512, 256, 0, stream>>>(Xq, Sq, Vfrag, out);
}